// Round 10
// baseline (414.277 us; speedup 1.0000x reference)
//
#include <hip/hip_runtime.h>
#include <math.h>

// Problem constants: EMBED=256, HEADS=8, LEVELS=1, POINTS=4, QUEUE=2, 200x200
#define NQ    40000
#define EMB   256
#define NHEAD 8
#define HDIM  32
#define HB    200
#define WB    200
#define NCOL  192     // 128 off cols + 64 aw cols
#define HPIX  2560000 // per-head vout plane: 80000 pixels * 32 dims

typedef __attribute__((ext_vector_type(8))) __bf16 bf16x8;
typedef __attribute__((ext_vector_type(4))) float f32x4;

static __device__ __forceinline__ unsigned short f2bf(float f) {
  unsigned u = __float_as_uint(f);
  u = u + 0x7fffu + ((u >> 16) & 1u);   // round-to-nearest-even
  return (unsigned short)(u >> 16);
}
static __device__ __forceinline__ float bf2f(unsigned short s) {
  return __uint_as_float(((unsigned)s) << 16);
}
// accumulate 8 bf16 (one uint4) into two named float4s (spill-safe)
static __device__ __forceinline__ void accp(float4& lo4, float4& hi4, uint4 u, float w) {
  lo4.x += w * __uint_as_float(u.x << 16);
  lo4.y += w * __uint_as_float(u.x & 0xffff0000u);
  lo4.z += w * __uint_as_float(u.y << 16);
  lo4.w += w * __uint_as_float(u.y & 0xffff0000u);
  hi4.x += w * __uint_as_float(u.z << 16);
  hi4.y += w * __uint_as_float(u.z & 0xffff0000u);
  hi4.z += w * __uint_as_float(u.w << 16);
  hi4.w += w * __uint_as_float(u.w & 0xffff0000u);
}

// ---------------------------------------------------------------------------
// conv_w: transposed bf16 weights + combined bias (tiny, one-shot)
// ---------------------------------------------------------------------------
__global__ __launch_bounds__(256) void conv_w(
    const float* __restrict__ W_off, const float* __restrict__ b_off,
    const float* __restrict__ W_attn, const float* __restrict__ b_attn,
    const float* __restrict__ W_val, const float* __restrict__ W_out,
    unsigned short* __restrict__ Wc1t, unsigned short* __restrict__ Wvt,
    unsigned short* __restrict__ Wot, float* __restrict__ bc1)
{
  int idx = blockIdx.x * 256 + threadIdx.x;
  if (idx < 98304) {                       // Wc1t [192][512]
    int n = idx >> 9, k = idx & 511;
    float v = (n < 128) ? W_off[(size_t)k * 128 + n] : W_attn[(size_t)k * 64 + (n - 128)];
    Wc1t[idx] = f2bf(v);
  } else if (idx < 163840) {               // Wvt [256][256]
    int j = idx - 98304;
    int n = j >> 8, k = j & 255;
    Wvt[j] = f2bf(W_val[(size_t)k * 256 + n]);
  } else if (idx < 229376) {               // Wot [256][256]
    int j = idx - 163840;
    int n = j >> 8, k = j & 255;
    Wot[j] = f2bf(W_out[(size_t)k * 256 + n]);
  } else if (idx < 229568) {               // bc1 [192]
    int n = idx - 229376;
    bc1[n] = (n < 128) ? b_off[n] : b_attn[n - 128];
  }
}

// ---------------------------------------------------------------------------
// Register GEMM. C[BM x N] tile = A @ Bt^T + bias.
// Round-10 change (isolated lever): BM is a template param, set to 16.
// Round-9 counters: occupancy pinned at 31% by GRID SIZE (1250 blocks =
// 4.9/CU), not LDS/VGPR. BM 32->16 doubles every grid, halves LDS (8.2 KB)
// and acc regs -> ~8 resident blocks/CU reachable. A-frags come from the
// shared LDS tile so waves duplicate nothing (round-1 failure N/A).
// AMODE 1 = fp32 [M][256] staged; 2 = synth q2 staged (half0 value, half1
// query+qpos); 4 = bf16 head-major [h][NQ][32] direct.
// Staged A: BM x 256 bf16 LDS half-tile, XOR-swizzled 16B chunks
// (slot = c ^ (r&7)); K=512 stages two halves. Block = 4 waves 1m x 4n.
// OMODE 0 = fp32 direct (+resid); 1 = bf16 row-major; 2 = bf16 head-major.
// ---------------------------------------------------------------------------
template<int K, int N, int BM, int AMODE, int OMODE, bool RESID>
__global__ __launch_bounds__(256, 4) void rb_gemm(
    const void* __restrict__ Aptr, const void* __restrict__ Aq2a,
    const void* __restrict__ Aq2b, const unsigned short* __restrict__ Bt,
    const float* __restrict__ bias, const float* __restrict__ resid,
    void* __restrict__ outp)
{
  constexpr int MFR = BM / 16;             // 16-row m-frags
  constexpr int NFR = N / 64;              // 16-col n-frags per wave
  constexpr int NP  = N + 8;
  constexpr int ATB = (AMODE == 1 || AMODE == 2) ? BM * 512 : 0;
  constexpr int TRB = (OMODE != 0) ? BM * NP * 2 : 0;
  constexpr int MXB = (ATB > TRB) ? ATB : TRB;
  constexpr int LDSB = (MXB > 64) ? MXB : 64;
  __shared__ __align__(16) char lds[LDSB];
  unsigned short* trn = (unsigned short*)lds;

  const int t = threadIdx.x;
  const int m0 = blockIdx.x * BM;
  const int wid = t >> 6, lane = t & 63;
  const int wn = wid * (N / 4);
  const int lr = lane & 15, quad = lane >> 4;

  auto cvt_store = [&](int r, int c, float4 f0, float4 f1) {
    union { unsigned short us[8]; uint4 v; } u;
    u.us[0] = f2bf(f0.x); u.us[1] = f2bf(f0.y);
    u.us[2] = f2bf(f0.z); u.us[3] = f2bf(f0.w);
    u.us[4] = f2bf(f1.x); u.us[5] = f2bf(f1.y);
    u.us[6] = f2bf(f1.z); u.us[7] = f2bf(f1.w);
    *(uint4*)(lds + (size_t)r * 512 + ((c ^ (r & 7)) * 16)) = u.v;
  };

  // stage one 256-wide K-half (hh) of rows m0..m0+BM into the LDS tile.
  // thread owns col-chunk c = t&31 (8 floats), rows r0 + 8l; 2-row batches
  // keep live registers <= 32 (spill-safe).
  auto stage_h = [&](int hh) {
    const int c = t & 31, r0 = t >> 5;
    constexpr int RPT = BM / 8;            // rows per thread
    if (AMODE == 1 || hh == 0) {
      #pragma unroll
      for (int g = 0; g < RPT / 2; g++) {
        float4 f[2][2];
        #pragma unroll
        for (int l = 0; l < 2; l++) {
          const float* s = (const float*)Aptr
              + (size_t)(m0 + r0 + 8 * (g * 2 + l)) * 256 + c * 8;
          f[l][0] = *(const float4*)s; f[l][1] = *(const float4*)(s + 4);
        }
        #pragma unroll
        for (int l = 0; l < 2; l++)
          cvt_store(r0 + 8 * (g * 2 + l), c, f[l][0], f[l][1]);
      }
    } else {
      #pragma unroll
      for (int g = 0; g < RPT / 2; g++) {
        float4 fq[2][2], fp[2][2];
        #pragma unroll
        for (int l = 0; l < 2; l++) {
          int row = m0 + r0 + 8 * (g * 2 + l);
          const float* sq = (const float*)Aq2a + (size_t)row * 256 + c * 8;
          const float* sp = (const float*)Aq2b + (size_t)row * 256 + c * 8;
          fq[l][0] = *(const float4*)sq; fq[l][1] = *(const float4*)(sq + 4);
          fp[l][0] = *(const float4*)sp; fp[l][1] = *(const float4*)(sp + 4);
        }
        #pragma unroll
        for (int l = 0; l < 2; l++) {
          float4 f0 = make_float4(fq[l][0].x + fp[l][0].x, fq[l][0].y + fp[l][0].y,
                                  fq[l][0].z + fp[l][0].z, fq[l][0].w + fp[l][0].w);
          float4 f1 = make_float4(fq[l][1].x + fp[l][1].x, fq[l][1].y + fp[l][1].y,
                                  fq[l][1].z + fp[l][1].z, fq[l][1].w + fp[l][1].w);
          cvt_store(r0 + 8 * (g * 2 + l), c, f0, f1);
        }
      }
    }
  };

  f32x4 acc[MFR][NFR];
  #pragma unroll
  for (int i = 0; i < MFR; i++)
    #pragma unroll
    for (int n = 0; n < NFR; n++) acc[i][n] = (f32x4){0.f, 0.f, 0.f, 0.f};

  auto loadB = [&](bf16x8* dst, int k0) {  // k0 = global K offset
    #pragma unroll
    for (int n = 0; n < NFR; n++)
      dst[n] = *(const bf16x8*)(Bt + (size_t)(wn + n * 16 + lr) * K + k0 + quad * 8);
  };
  auto loadA_lds = [&](bf16x8* dst, int lk) {  // lk = offset within half
    const int cb = (lk >> 3) + quad;
    const int sw = (cb ^ (lr & 7)) * 16;
    #pragma unroll
    for (int i = 0; i < MFR; i++)
      dst[i] = *(const bf16x8*)(lds + (size_t)(lr + i * 16) * 512 + sw);
  };
  auto loadA_dir = [&](bf16x8* dst, int k0) {
    if constexpr (AMODE == 0) {
      const unsigned short* A = (const unsigned short*)Aptr;
      #pragma unroll
      for (int i = 0; i < MFR; i++)
        dst[i] = *(const bf16x8*)(A + (size_t)(m0 + lr + i * 16) * K + k0 + quad * 8);
    } else {                               // AMODE == 4: head-major
      const unsigned short* A = (const unsigned short*)Aptr;
      const int h = k0 >> 5;
      #pragma unroll
      for (int i = 0; i < MFR; i++)
        dst[i] = *(const bf16x8*)(A + (size_t)h * NQ * 32
                                    + (size_t)(m0 + lr + i * 16) * 32 + quad * 8);
    }
  };

  if constexpr (AMODE == 1 || AMODE == 2) {
    constexpr int NH = K / 256;            // staged halves
    #pragma unroll
    for (int hh = 0; hh < NH; hh++) {
      if (hh) __syncthreads();             // WAR: prev half reads done
      stage_h(hh);
      __syncthreads();
      bf16x8 bcur[NFR], af[MFR];
      loadB(bcur, hh * 256);
      loadA_lds(af, 0);
      #pragma unroll
      for (int ks = 0; ks < 8; ks++) {
        bf16x8 bn[NFR], an[MFR];
        if (ks < 7) {                      // prefetch-1 within half
          loadB(bn, hh * 256 + (ks + 1) * 32);
          loadA_lds(an, (ks + 1) * 32);
        }
        #pragma unroll
        for (int i = 0; i < MFR; i++)
          #pragma unroll
          for (int n = 0; n < NFR; n++)
            acc[i][n] = __builtin_amdgcn_mfma_f32_16x16x32_bf16(af[i], bcur[n], acc[i][n], 0, 0, 0);
        if (ks < 7) {
          #pragma unroll
          for (int n = 0; n < NFR; n++) bcur[n] = bn[n];
          #pragma unroll
          for (int i = 0; i < MFR; i++) af[i] = an[i];
        }
      }
    }
  } else {
    constexpr int NK = K / 32;
    bf16x8 bcur[NFR], af[MFR];
    loadB(bcur, 0);
    loadA_dir(af, 0);
    #pragma unroll
    for (int ks = 0; ks < NK; ks++) {
      bf16x8 bn[NFR], an[MFR];
      if (ks + 1 < NK) {
        loadB(bn, (ks + 1) * 32);
        loadA_dir(an, (ks + 1) * 32);
      }
      #pragma unroll
      for (int i = 0; i < MFR; i++)
        #pragma unroll
        for (int n = 0; n < NFR; n++)
          acc[i][n] = __builtin_amdgcn_mfma_f32_16x16x32_bf16(af[i], bcur[n], acc[i][n], 0, 0, 0);
      if (ks + 1 < NK) {
        #pragma unroll
        for (int n = 0; n < NFR; n++) bcur[n] = bn[n];
        #pragma unroll
        for (int i = 0; i < MFR; i++) af[i] = an[i];
      }
    }
  }

  // epilogue: C/D layout col=lane&15, row=quad*4+reg
  if constexpr (OMODE == 0) {
    #pragma unroll
    for (int i = 0; i < MFR; i++) {
      int rowb = m0 + i * 16 + quad * 4;
      #pragma unroll
      for (int n = 0; n < NFR; n++) {
        int col = wn + n * 16 + lr;
        float bsv = bias[col];
        #pragma unroll
        for (int r = 0; r < 4; r++) {
          int rr = rowb + r;
          float v = acc[i][n][r] + bsv;
          if (RESID) v += resid[(size_t)rr * N + col];
          ((float*)outp)[(size_t)rr * N + col] = v;
        }
      }
    }
  } else {
    __syncthreads();                       // A-tile -> trn buffer reuse
    #pragma unroll
    for (int i = 0; i < MFR; i++) {
      #pragma unroll
      for (int n = 0; n < NFR; n++) {
        int col = wn + n * 16 + lr;
        float bsv = bias[col];
        #pragma unroll
        for (int r = 0; r < 4; r++) {
          int rl = i * 16 + quad * 4 + r;
          trn[rl * NP + col] = f2bf(acc[i][n][r] + bsv);
        }
      }
    }
    __syncthreads();
    constexpr int TOT = (BM * N) / 8;      // total uint4 chunks
    constexpr int NL = (TOT + 255) / 256;
    #pragma unroll
    for (int l = 0; l < NL; l++) {
      int c = t + l * 256;
      if (TOT % 256 == 0 || c < TOT) {
        int row = c / (N / 8);
        int coloff = (c % (N / 8)) * 8;
        uint4 d = *(const uint4*)(trn + row * NP + coloff);
        unsigned short* op = (unsigned short*)outp;
        if constexpr (OMODE == 2)
          op += (size_t)(coloff >> 5) * HPIX + (size_t)(m0 + row) * 32 + (coloff & 31);
        else
          op += (size_t)(m0 + row) * N + coloff;
        *(uint4*)op = d;
      }
    }
  }
}

// ---------------------------------------------------------------------------
// K3: deformable sampling + queue mean, HEAD<->XCD AFFINE (round-8 verified).
// Block = 64 queries x ONE head (h = blockIdx.x & 7); round-robin dispatch
// gives each XCD (mostly) one 5 MB head plane -> ~L2-resident gather.
// ---------------------------------------------------------------------------
__global__ __launch_bounds__(256) void k3_sample(
    const unsigned short* __restrict__ raw1, const float* __restrict__ refp,
    const unsigned short* __restrict__ vh, unsigned short* __restrict__ msd)
{
  __shared__ int4   sidx[512];
  __shared__ float4 swgt[512];
  const int t = threadIdx.x;
  const int h  = blockIdx.x & 7;          // head = XCD slot
  const int q0 = (blockIdx.x >> 3) * 64;  // 625 query-groups x 8 heads

  #pragma unroll
  for (int ee = 0; ee < 2; ee++) {
    const int e = t + ee * 256;           // e = qi*8 + b*4 + p
    const int qi = e >> 3, b = (e >> 2) & 1, p = e & 3;
    const int q = q0 + qi;
    const unsigned short* r = raw1 + (size_t)q * NCOL;
    float ox = bf2f(r[h * 16 + b * 8 + p * 2 + 0]);
    float oy = bf2f(r[h * 16 + b * 8 + p * 2 + 1]);
    float l0 = bf2f(r[128 + h * 8 + b * 4 + 0]);
    float l1 = bf2f(r[128 + h * 8 + b * 4 + 1]);
    float l2 = bf2f(r[128 + h * 8 + b * 4 + 2]);
    float l3 = bf2f(r[128 + h * 8 + b * 4 + 3]);
    float mx = fmaxf(fmaxf(l0, l1), fmaxf(l2, l3));
    float e0 = expf(l0 - mx), e1 = expf(l1 - mx);
    float e2 = expf(l2 - mx), e3 = expf(l3 - mx);
    float ssum = e0 + e1 + e2 + e3;
    float ep = (p == 0) ? e0 : (p == 1) ? e1 : (p == 2) ? e2 : e3;
    float aw = ep / ssum * 0.5f;          // fold queue-mean 0.5
    float rx = refp[((size_t)b * NQ + q) * 2 + 0];
    float ry = refp[((size_t)b * NQ + q) * 2 + 1];
    float px = rx * (float)WB + ox - 0.5f;
    float py = ry * (float)HB + oy - 0.5f;
    float x0f = floorf(px), y0f = floorf(py);
    float lx = px - x0f, ly = py - y0f;
    int x0 = (int)x0f, y0 = (int)y0f, x1 = x0 + 1, y1 = y0 + 1;
    int x0c = min(max(x0, 0), WB - 1), x1c = min(max(x1, 0), WB - 1);
    int y0c = min(max(y0, 0), HB - 1), y1c = min(max(y1, 0), HB - 1);
    float vx0 = ((unsigned)x0 < (unsigned)WB) ? 1.f : 0.f;
    float vx1 = ((unsigned)x1 < (unsigned)WB) ? 1.f : 0.f;
    float vy0 = ((unsigned)y0 < (unsigned)HB) ? 1.f : 0.f;
    float vy1 = ((unsigned)y1 < (unsigned)HB) ? 1.f : 0.f;
    const int pb = b * NQ;                // per-queue pixel plane offset
    int4 ix;
    ix.x = pb + y0c * WB + x0c;
    ix.y = pb + y0c * WB + x1c;
    ix.z = pb + y1c * WB + x0c;
    ix.w = pb + y1c * WB + x1c;
    float4 wv;
    wv.x = aw * (1.f - lx) * (1.f - ly) * vx0 * vy0;
    wv.y = aw * lx * (1.f - ly) * vx1 * vy0;
    wv.z = aw * (1.f - lx) * ly * vx0 * vy1;
    wv.w = aw * lx * ly * vx1 * vy1;
    sidx[e] = ix;
    swgt[e] = wv;
  }
  __syncthreads();

  // gather: thread = (qi, c); reads vh[h][pixel][c*8 .. c*8+8) as uint4
  const int qi = t >> 2, c = t & 3;
  const unsigned short* vb = vh + (size_t)h * HPIX + c * 8;
  float4 lo = {0.f, 0.f, 0.f, 0.f}, hi = lo;
  #pragma unroll
  for (int b = 0; b < 2; b++) {
    #pragma unroll
    for (int p = 0; p < 4; p++) {
      int ent = qi * 8 + b * 4 + p;
      int4 pix = sidx[ent];
      float4 wv = swgt[ent];
      accp(lo, hi, *(const uint4*)(vb + (size_t)pix.x * 32), wv.x);
      accp(lo, hi, *(const uint4*)(vb + (size_t)pix.y * 32), wv.y);
      accp(lo, hi, *(const uint4*)(vb + (size_t)pix.z * 32), wv.z);
      accp(lo, hi, *(const uint4*)(vb + (size_t)pix.w * 32), wv.w);
    }
  }
  union { unsigned short us[8]; uint4 v; } o;
  o.us[0] = f2bf(lo.x); o.us[1] = f2bf(lo.y);
  o.us[2] = f2bf(lo.z); o.us[3] = f2bf(lo.w);
  o.us[4] = f2bf(hi.x); o.us[5] = f2bf(hi.y);
  o.us[6] = f2bf(hi.z); o.us[7] = f2bf(hi.w);
  *(uint4*)(msd + (size_t)h * NQ * 32 + (size_t)(q0 + qi) * 32 + c * 8) = o.v;
}

// ---------------------------------------------------------------------------
extern "C" void kernel_launch(void* const* d_in, const int* in_sizes, int n_in,
                              void* d_out, int out_size, void* d_ws, size_t ws_size,
                              hipStream_t stream) {
  const float* query     = (const float*)d_in[0];
  const float* query_pos = (const float*)d_in[1];
  const float* value     = (const float*)d_in[2];
  const float* refp      = (const float*)d_in[3];
  // d_in[4]: spatial_shapes constant [200,200]
  const float* W_off  = (const float*)d_in[5];
  const float* b_off  = (const float*)d_in[6];
  const float* W_attn = (const float*)d_in[7];
  const float* b_attn = (const float*)d_in[8];
  const float* W_val  = (const float*)d_in[9];
  const float* b_val  = (const float*)d_in[10];
  const float* W_out  = (const float*)d_in[11];
  const float* b_out  = (const float*)d_in[12];
  float* out = (float*)d_out;

  char* ws = (char*)d_ws;
  unsigned short* raw1 = (unsigned short*)(ws);            // 40000*192*2 = 15,360,000
  unsigned short* vout = (unsigned short*)(ws + 15360000); // 80000*256*2 (head-major)
  unsigned short* msdb = (unsigned short*)(ws + 56320000); // 40000*256*2 (head-major)
  unsigned short* Wc1t = (unsigned short*)(ws + 76800000); // 192*512*2
  unsigned short* Wvt  = (unsigned short*)(ws + 76996608); // 256*256*2
  unsigned short* Wot  = (unsigned short*)(ws + 77127680); // 256*256*2
  float*          bc1  = (float*)(ws + 77258752);          // 192*4

  hipLaunchKernelGGL(conv_w, dim3(897), dim3(256), 0, stream,
                     W_off, b_off, W_attn, b_attn, W_val, W_out, Wc1t, Wvt, Wot, bc1);

  // k1: raw1 = q2 @ [W_off|W_attn] + bc1  (40000x512 @ 512x192),
  //     BM=16 two-half staged synth A (LDS 8.2 KB), bf16 out
  hipLaunchKernelGGL((rb_gemm<512, 192, 16, 2, 1, false>),
                     dim3(2500), dim3(256), 0, stream,
                     (const void*)value, (const void*)query, (const void*)query_pos,
                     Wc1t, bc1, (const float*)nullptr, (void*)raw1);
  // k2: v = value @ W_val + b_val  (80000x256 @ 256x256), BM=16 staged fp32 A,
  //     head-major bf16 out
  hipLaunchKernelGGL((rb_gemm<256, 256, 16, 1, 2, false>),
                     dim3(5000), dim3(256), 0, stream,
                     (const void*)value, (const void*)nullptr, (const void*)nullptr,
                     Wvt, b_val, (const float*)nullptr, (void*)vout);
  // k3: head-XCD-affine sampling -> msd head-major (5000 blocks: 625 qg x 8 h)
  hipLaunchKernelGGL(k3_sample, dim3(5000), dim3(256), 0, stream,
                     raw1, refp, vout, msdb);
  // k4: out = msd @ W_out + b_out + query, BM=16 head-major bf16 A direct,
  //     fp32 out + resid
  hipLaunchKernelGGL((rb_gemm<256, 256, 16, 4, 0, true>),
                     dim3(2500), dim3(256), 0, stream,
                     (const void*)msdb, (const void*)nullptr, (const void*)nullptr,
                     Wot, b_out, query, (void*)out);
}

// Round 12
// 336.872 us; speedup vs baseline: 1.2298x; 1.2298x over previous
//
#include <hip/hip_runtime.h>
#include <math.h>

// Problem constants: EMBED=256, HEADS=8, LEVELS=1, POINTS=4, QUEUE=2, 200x200
#define NQ    40000
#define EMB   256
#define NHEAD 8
#define HDIM  32
#define HB    200
#define WB    200
#define NCOL  192     // 128 off cols + 64 aw cols
#define HPIX  2560000 // per-head vout plane: 80000 pixels * 32 dims

typedef __attribute__((ext_vector_type(8))) __bf16 bf16x8;
typedef __attribute__((ext_vector_type(4))) float f32x4;

static __device__ __forceinline__ unsigned short f2bf(float f) {
  unsigned u = __float_as_uint(f);
  u = u + 0x7fffu + ((u >> 16) & 1u);   // round-to-nearest-even
  return (unsigned short)(u >> 16);
}
static __device__ __forceinline__ float bf2f(unsigned short s) {
  return __uint_as_float(((unsigned)s) << 16);
}
// accumulate 8 bf16 (one uint4) into two named float4s (spill-safe)
static __device__ __forceinline__ void accp(float4& lo4, float4& hi4, uint4 u, float w) {
  lo4.x += w * __uint_as_float(u.x << 16);
  lo4.y += w * __uint_as_float(u.x & 0xffff0000u);
  lo4.z += w * __uint_as_float(u.y << 16);
  lo4.w += w * __uint_as_float(u.y & 0xffff0000u);
  hi4.x += w * __uint_as_float(u.z << 16);
  hi4.y += w * __uint_as_float(u.z & 0xffff0000u);
  hi4.z += w * __uint_as_float(u.w << 16);
  hi4.w += w * __uint_as_float(u.w & 0xffff0000u);
}

// ---------------------------------------------------------------------------
// conv_w: transposed bf16 weights + combined bias (tiny, one-shot)
// ---------------------------------------------------------------------------
__global__ __launch_bounds__(256) void conv_w(
    const float* __restrict__ W_off, const float* __restrict__ b_off,
    const float* __restrict__ W_attn, const float* __restrict__ b_attn,
    const float* __restrict__ W_val, const float* __restrict__ W_out,
    unsigned short* __restrict__ Wc1t, unsigned short* __restrict__ Wvt,
    unsigned short* __restrict__ Wot, float* __restrict__ bc1)
{
  int idx = blockIdx.x * 256 + threadIdx.x;
  if (idx < 98304) {                       // Wc1t [192][512]
    int n = idx >> 9, k = idx & 511;
    float v = (n < 128) ? W_off[(size_t)k * 128 + n] : W_attn[(size_t)k * 64 + (n - 128)];
    Wc1t[idx] = f2bf(v);
  } else if (idx < 163840) {               // Wvt [256][256]
    int j = idx - 98304;
    int n = j >> 8, k = j & 255;
    Wvt[j] = f2bf(W_val[(size_t)k * 256 + n]);
  } else if (idx < 229376) {               // Wot [256][256]
    int j = idx - 163840;
    int n = j >> 8, k = j & 255;
    Wot[j] = f2bf(W_out[(size_t)k * 256 + n]);
  } else if (idx < 229568) {               // bc1 [192]
    int n = idx - 229376;
    bc1[n] = (n < 128) ? b_off[n] : b_attn[n - 128];
  }
}

// ---------------------------------------------------------------------------
// GEMM body (round-9 verified structure, BM=32, shared by k12 and k4).
// C[32 x N] = A[32 x K] @ Bt[N x K]^T + bias. Block = 4 waves 1m x 4n.
// Staged A: 32 x 256 bf16 LDS half-tile (16.4 KB), XOR-swizzled 16B chunks
// (slot = c ^ (r&7)); K=512 stages two halves in sequence.
// ROUND-12 FIX: staged A sources are ALWAYS [M][256] fp32 arrays (value /
// query / qpos) — stage_h reads with stride 256; hh selects WHICH tensor,
// never a column offset. (Round-11 refactor wrote row*K + hh*256: for k1
// K=512 that read value with stride 512 -> wrong rows -> absmax 0.134.)
// AMODE 1 = fp32 [M][256] staged; 2 = synth q2 staged (half0 value, half1
// query+qpos); 0 = bf16 [M][K] direct; 4 = bf16 head-major [h][NQ][32].
// OMODE 0 = fp32 direct (+resid); 1 = bf16 row-major; 2 = bf16 head-major.
// Round-10 lesson baked in: BM=32 stays — BM=16 doubled B-load per MFMA.
// ---------------------------------------------------------------------------
template<int K, int N, int AMODE, int OMODE, bool RESID>
static __device__ __forceinline__ void gemm_body(
    int bx, char* lds,
    const void* __restrict__ Aptr, const void* __restrict__ Aq2a,
    const void* __restrict__ Aq2b, const unsigned short* __restrict__ Bt,
    const float* __restrict__ bias, const float* __restrict__ resid,
    void* __restrict__ outp)
{
  constexpr int NFR = N / 64;              // 16-col n-frags per wave
  constexpr int NP  = N + 8;
  unsigned short* trn = (unsigned short*)lds;

  const int t = threadIdx.x;
  const int m0 = bx * 32;
  const int wid = t >> 6, lane = t & 63;
  const int wn = wid * (N / 4);
  const int lr = lane & 15, quad = lane >> 4;

  auto cvt_store = [&](int r, int c, float4 f0, float4 f1) {
    union { unsigned short us[8]; uint4 v; } u;
    u.us[0] = f2bf(f0.x); u.us[1] = f2bf(f0.y);
    u.us[2] = f2bf(f0.z); u.us[3] = f2bf(f0.w);
    u.us[4] = f2bf(f1.x); u.us[5] = f2bf(f1.y);
    u.us[6] = f2bf(f1.z); u.us[7] = f2bf(f1.w);
    *(uint4*)(lds + (size_t)r * 512 + ((c ^ (r & 7)) * 16)) = u.v;
  };

  // stage one 256-wide K-half (hh): thread owns col-chunk c = t&31,
  // rows r0 + 8l in 2-row batches (<=32 live regs, spill-safe).
  // Sources are [M][256] fp32: stride 256 ALWAYS (see round-12 fix note).
  auto stage_h = [&](int hh) {
    const int c = t & 31, r0 = t >> 5;
    if (AMODE == 1 || hh == 0) {
      #pragma unroll
      for (int g = 0; g < 2; g++) {
        float4 f[2][2];
        #pragma unroll
        for (int l = 0; l < 2; l++) {
          const float* s = (const float*)Aptr
              + (size_t)(m0 + r0 + 8 * (g * 2 + l)) * 256 + c * 8;
          f[l][0] = *(const float4*)s; f[l][1] = *(const float4*)(s + 4);
        }
        #pragma unroll
        for (int l = 0; l < 2; l++)
          cvt_store(r0 + 8 * (g * 2 + l), c, f[l][0], f[l][1]);
      }
    } else {
      #pragma unroll
      for (int g = 0; g < 2; g++) {
        float4 fq[2][2], fp[2][2];
        #pragma unroll
        for (int l = 0; l < 2; l++) {
          int row = m0 + r0 + 8 * (g * 2 + l);
          const float* sq = (const float*)Aq2a + (size_t)row * 256 + c * 8;
          const float* sp = (const float*)Aq2b + (size_t)row * 256 + c * 8;
          fq[l][0] = *(const float4*)sq; fq[l][1] = *(const float4*)(sq + 4);
          fp[l][0] = *(const float4*)sp; fp[l][1] = *(const float4*)(sp + 4);
        }
        #pragma unroll
        for (int l = 0; l < 2; l++) {
          float4 f0 = make_float4(fq[l][0].x + fp[l][0].x, fq[l][0].y + fp[l][0].y,
                                  fq[l][0].z + fp[l][0].z, fq[l][0].w + fp[l][0].w);
          float4 f1 = make_float4(fq[l][1].x + fp[l][1].x, fq[l][1].y + fp[l][1].y,
                                  fq[l][1].z + fp[l][1].z, fq[l][1].w + fp[l][1].w);
          cvt_store(r0 + 8 * (g * 2 + l), c, f0, f1);
        }
      }
    }
  };

  f32x4 acc[2][NFR];
  #pragma unroll
  for (int i = 0; i < 2; i++)
    #pragma unroll
    for (int n = 0; n < NFR; n++) acc[i][n] = (f32x4){0.f, 0.f, 0.f, 0.f};

  auto loadB = [&](bf16x8* dst, int k0) {  // k0 = global K offset
    #pragma unroll
    for (int n = 0; n < NFR; n++)
      dst[n] = *(const bf16x8*)(Bt + (size_t)(wn + n * 16 + lr) * K + k0 + quad * 8);
  };
  auto loadA_lds = [&](bf16x8* dst, int lk) {  // lk = offset within half
    const int cb = (lk >> 3) + quad;
    const int sw = (cb ^ (lr & 7)) * 16;
    #pragma unroll
    for (int i = 0; i < 2; i++)
      dst[i] = *(const bf16x8*)(lds + (size_t)(lr + i * 16) * 512 + sw);
  };
  auto loadA_dir = [&](bf16x8* dst, int k0) {
    if constexpr (AMODE == 0) {
      const unsigned short* A = (const unsigned short*)Aptr;
      #pragma unroll
      for (int i = 0; i < 2; i++)
        dst[i] = *(const bf16x8*)(A + (size_t)(m0 + lr + i * 16) * K + k0 + quad * 8);
    } else {                               // AMODE == 4: head-major
      const unsigned short* A = (const unsigned short*)Aptr;
      const int h = k0 >> 5;
      #pragma unroll
      for (int i = 0; i < 2; i++)
        dst[i] = *(const bf16x8*)(A + (size_t)h * NQ * 32
                                    + (size_t)(m0 + lr + i * 16) * 32 + quad * 8);
    }
  };

  if constexpr (AMODE == 1 || AMODE == 2) {
    constexpr int NH = K / 256;            // staged halves
    #pragma unroll
    for (int hh = 0; hh < NH; hh++) {
      if (hh) __syncthreads();             // WAR: prev half reads done
      stage_h(hh);
      __syncthreads();
      bf16x8 bcur[NFR], af[2];
      loadB(bcur, hh * 256);
      loadA_lds(af, 0);
      #pragma unroll
      for (int ks = 0; ks < 8; ks++) {
        bf16x8 bn[NFR], an[2];
        if (ks < 7) {                      // prefetch-1 within half
          loadB(bn, hh * 256 + (ks + 1) * 32);
          loadA_lds(an, (ks + 1) * 32);
        }
        #pragma unroll
        for (int i = 0; i < 2; i++)
          #pragma unroll
          for (int n = 0; n < NFR; n++)
            acc[i][n] = __builtin_amdgcn_mfma_f32_16x16x32_bf16(af[i], bcur[n], acc[i][n], 0, 0, 0);
        if (ks < 7) {
          #pragma unroll
          for (int n = 0; n < NFR; n++) bcur[n] = bn[n];
          af[0] = an[0]; af[1] = an[1];
        }
      }
    }
  } else {
    constexpr int NK = K / 32;
    bf16x8 bcur[NFR], af[2];
    loadB(bcur, 0);
    loadA_dir(af, 0);
    #pragma unroll
    for (int ks = 0; ks < NK; ks++) {
      bf16x8 bn[NFR], an[2];
      if (ks + 1 < NK) {
        loadB(bn, (ks + 1) * 32);
        loadA_dir(an, (ks + 1) * 32);
      }
      #pragma unroll
      for (int i = 0; i < 2; i++)
        #pragma unroll
        for (int n = 0; n < NFR; n++)
          acc[i][n] = __builtin_amdgcn_mfma_f32_16x16x32_bf16(af[i], bcur[n], acc[i][n], 0, 0, 0);
      if (ks + 1 < NK) {
        #pragma unroll
        for (int n = 0; n < NFR; n++) bcur[n] = bn[n];
        af[0] = an[0]; af[1] = an[1];
      }
    }
  }

  // epilogue: C/D layout col=lane&15, row=quad*4+reg
  if constexpr (OMODE == 0) {
    #pragma unroll
    for (int i = 0; i < 2; i++) {
      int rowb = m0 + i * 16 + quad * 4;
      #pragma unroll
      for (int n = 0; n < NFR; n++) {
        int col = wn + n * 16 + lr;
        float bsv = bias[col];
        #pragma unroll
        for (int r = 0; r < 4; r++) {
          int rr = rowb + r;
          float v = acc[i][n][r] + bsv;
          if (RESID) v += resid[(size_t)rr * N + col];
          ((float*)outp)[(size_t)rr * N + col] = v;
        }
      }
    }
  } else {
    __syncthreads();                       // A-tile -> trn buffer reuse
    #pragma unroll
    for (int i = 0; i < 2; i++) {
      #pragma unroll
      for (int n = 0; n < NFR; n++) {
        int col = wn + n * 16 + lr;
        float bsv = bias[col];
        #pragma unroll
        for (int r = 0; r < 4; r++) {
          int rl = i * 16 + quad * 4 + r;
          trn[rl * NP + col] = f2bf(acc[i][n][r] + bsv);
        }
      }
    }
    __syncthreads();
    constexpr int NCH = (32 * N) / 2048;   // uint4 chunks per thread
    #pragma unroll
    for (int l = 0; l < NCH; l++) {
      int c = t + l * 256;
      int row = c / (N / 8);
      int coloff = (c % (N / 8)) * 8;
      uint4 d = *(const uint4*)(trn + row * NP + coloff);
      unsigned short* op = (unsigned short*)outp;
      if constexpr (OMODE == 2)
        op += (size_t)(coloff >> 5) * HPIX + (size_t)(m0 + row) * 32 + (coloff & 31);
      else
        op += (size_t)(m0 + row) * N + coloff;
      *(uint4*)op = d;
    }
  }
}

// ---------------------------------------------------------------------------
// k12: fused k1 + k2 (independent GEMMs, one grid). Same BM=32 per-wave
// efficiency, 3750 blocks = 14.6/CU supply (round 9 gave k1 only 4.9/CU ->
// 31% occupancy); kills one launch ramp/tail; k1's value-half rides k2's
// value stream in L3.
// ---------------------------------------------------------------------------
__global__ __launch_bounds__(256, 4) void k12(
    const float* __restrict__ value, const float* __restrict__ query,
    const float* __restrict__ qpos, const unsigned short* __restrict__ Wc1t,
    const unsigned short* __restrict__ Wvt, const float* __restrict__ bc1,
    const float* __restrict__ b_val, unsigned short* __restrict__ raw1,
    unsigned short* __restrict__ vout)
{
  __shared__ __align__(16) char lds[16896];  // max(A-half 16384, k2 trn 16896)
  const int bx = blockIdx.x;
  if (bx < 1250) {
    // k1: raw1 = [value | query+qpos] @ Wc1t^T + bc1  (40000x512 @ 512x192)
    gemm_body<512, 192, 2, 1, false>(bx, lds, value, query, qpos,
                                     Wc1t, bc1, nullptr, raw1);
  } else {
    // k2: vout = value @ Wvt^T + b_val (80000x256 @ 256x256), head-major out
    gemm_body<256, 256, 1, 2, false>(bx - 1250, lds, value, nullptr, nullptr,
                                     Wvt, b_val, nullptr, vout);
  }
}

// ---------------------------------------------------------------------------
// k4: out = msd @ Wot^T + b_out + query (head-major bf16 A direct, fp32 out)
// ---------------------------------------------------------------------------
__global__ __launch_bounds__(256, 4) void k4g(
    const unsigned short* __restrict__ msd, const unsigned short* __restrict__ Wot,
    const float* __restrict__ b_out, const float* __restrict__ query,
    float* __restrict__ out)
{
  __shared__ __align__(16) char lds[64];
  gemm_body<256, 256, 4, 0, true>(blockIdx.x, lds, msd, nullptr, nullptr,
                                  Wot, b_out, query, out);
}

// ---------------------------------------------------------------------------
// K3: deformable sampling + queue mean, HEAD<->XCD AFFINE (round-8 verified).
// Block = 64 queries x ONE head (h = blockIdx.x & 7); round-robin dispatch
// gives each XCD (mostly) one 5 MB head plane -> ~L2-resident gather.
// ---------------------------------------------------------------------------
__global__ __launch_bounds__(256) void k3_sample(
    const unsigned short* __restrict__ raw1, const float* __restrict__ refp,
    const unsigned short* __restrict__ vh, unsigned short* __restrict__ msd)
{
  __shared__ int4   sidx[512];
  __shared__ float4 swgt[512];
  const int t = threadIdx.x;
  const int h  = blockIdx.x & 7;          // head = XCD slot
  const int q0 = (blockIdx.x >> 3) * 64;  // 625 query-groups x 8 heads

  #pragma unroll
  for (int ee = 0; ee < 2; ee++) {
    const int e = t + ee * 256;           // e = qi*8 + b*4 + p
    const int qi = e >> 3, b = (e >> 2) & 1, p = e & 3;
    const int q = q0 + qi;
    const unsigned short* r = raw1 + (size_t)q * NCOL;
    float ox = bf2f(r[h * 16 + b * 8 + p * 2 + 0]);
    float oy = bf2f(r[h * 16 + b * 8 + p * 2 + 1]);
    float l0 = bf2f(r[128 + h * 8 + b * 4 + 0]);
    float l1 = bf2f(r[128 + h * 8 + b * 4 + 1]);
    float l2 = bf2f(r[128 + h * 8 + b * 4 + 2]);
    float l3 = bf2f(r[128 + h * 8 + b * 4 + 3]);
    float mx = fmaxf(fmaxf(l0, l1), fmaxf(l2, l3));
    float e0 = expf(l0 - mx), e1 = expf(l1 - mx);
    float e2 = expf(l2 - mx), e3 = expf(l3 - mx);
    float ssum = e0 + e1 + e2 + e3;
    float ep = (p == 0) ? e0 : (p == 1) ? e1 : (p == 2) ? e2 : e3;
    float aw = ep / ssum * 0.5f;          // fold queue-mean 0.5
    float rx = refp[((size_t)b * NQ + q) * 2 + 0];
    float ry = refp[((size_t)b * NQ + q) * 2 + 1];
    float px = rx * (float)WB + ox - 0.5f;
    float py = ry * (float)HB + oy - 0.5f;
    float x0f = floorf(px), y0f = floorf(py);
    float lx = px - x0f, ly = py - y0f;
    int x0 = (int)x0f, y0 = (int)y0f, x1 = x0 + 1, y1 = y0 + 1;
    int x0c = min(max(x0, 0), WB - 1), x1c = min(max(x1, 0), WB - 1);
    int y0c = min(max(y0, 0), HB - 1), y1c = min(max(y1, 0), HB - 1);
    float vx0 = ((unsigned)x0 < (unsigned)WB) ? 1.f : 0.f;
    float vx1 = ((unsigned)x1 < (unsigned)WB) ? 1.f : 0.f;
    float vy0 = ((unsigned)y0 < (unsigned)HB) ? 1.f : 0.f;
    float vy1 = ((unsigned)y1 < (unsigned)HB) ? 1.f : 0.f;
    const int pb = b * NQ;                // per-queue pixel plane offset
    int4 ix;
    ix.x = pb + y0c * WB + x0c;
    ix.y = pb + y0c * WB + x1c;
    ix.z = pb + y1c * WB + x0c;
    ix.w = pb + y1c * WB + x1c;
    float4 wv;
    wv.x = aw * (1.f - lx) * (1.f - ly) * vx0 * vy0;
    wv.y = aw * lx * (1.f - ly) * vx1 * vy0;
    wv.z = aw * (1.f - lx) * ly * vx0 * vy1;
    wv.w = aw * lx * ly * vx1 * vy1;
    sidx[e] = ix;
    swgt[e] = wv;
  }
  __syncthreads();

  // gather: thread = (qi, c); reads vh[h][pixel][c*8 .. c*8+8) as uint4
  const int qi = t >> 2, c = t & 3;
  const unsigned short* vb = vh + (size_t)h * HPIX + c * 8;
  float4 lo = {0.f, 0.f, 0.f, 0.f}, hi = lo;
  #pragma unroll
  for (int b = 0; b < 2; b++) {
    #pragma unroll
    for (int p = 0; p < 4; p++) {
      int ent = qi * 8 + b * 4 + p;
      int4 pix = sidx[ent];
      float4 wv = swgt[ent];
      accp(lo, hi, *(const uint4*)(vb + (size_t)pix.x * 32), wv.x);
      accp(lo, hi, *(const uint4*)(vb + (size_t)pix.y * 32), wv.y);
      accp(lo, hi, *(const uint4*)(vb + (size_t)pix.z * 32), wv.z);
      accp(lo, hi, *(const uint4*)(vb + (size_t)pix.w * 32), wv.w);
    }
  }
  union { unsigned short us[8]; uint4 v; } o;
  o.us[0] = f2bf(lo.x); o.us[1] = f2bf(lo.y);
  o.us[2] = f2bf(lo.z); o.us[3] = f2bf(lo.w);
  o.us[4] = f2bf(hi.x); o.us[5] = f2bf(hi.y);
  o.us[6] = f2bf(hi.z); o.us[7] = f2bf(hi.w);
  *(uint4*)(msd + (size_t)h * NQ * 32 + (size_t)(q0 + qi) * 32 + c * 8) = o.v;
}

// ---------------------------------------------------------------------------
extern "C" void kernel_launch(void* const* d_in, const int* in_sizes, int n_in,
                              void* d_out, int out_size, void* d_ws, size_t ws_size,
                              hipStream_t stream) {
  const float* query     = (const float*)d_in[0];
  const float* query_pos = (const float*)d_in[1];
  const float* value     = (const float*)d_in[2];
  const float* refp      = (const float*)d_in[3];
  // d_in[4]: spatial_shapes constant [200,200]
  const float* W_off  = (const float*)d_in[5];
  const float* b_off  = (const float*)d_in[6];
  const float* W_attn = (const float*)d_in[7];
  const float* b_attn = (const float*)d_in[8];
  const float* W_val  = (const float*)d_in[9];
  const float* b_val  = (const float*)d_in[10];
  const float* W_out  = (const float*)d_in[11];
  const float* b_out  = (const float*)d_in[12];
  float* out = (float*)d_out;

  char* ws = (char*)d_ws;
  unsigned short* raw1 = (unsigned short*)(ws);            // 40000*192*2 = 15,360,000
  unsigned short* vout = (unsigned short*)(ws + 15360000); // 80000*256*2 (head-major)
  unsigned short* msdb = (unsigned short*)(ws + 56320000); // 40000*256*2 (head-major)
  unsigned short* Wc1t = (unsigned short*)(ws + 76800000); // 192*512*2
  unsigned short* Wvt  = (unsigned short*)(ws + 76996608); // 256*256*2
  unsigned short* Wot  = (unsigned short*)(ws + 77127680); // 256*256*2
  float*          bc1  = (float*)(ws + 77258752);          // 192*4

  hipLaunchKernelGGL(conv_w, dim3(897), dim3(256), 0, stream,
                     W_off, b_off, W_attn, b_attn, W_val, W_out, Wc1t, Wvt, Wot, bc1);

  // k12: fused k1 (blocks 0-1249, BM=32 two-half staged synth A) +
  //      k2 (blocks 1250-3749, BM=32 staged fp32 A, head-major out)
  hipLaunchKernelGGL(k12, dim3(3750), dim3(256), 0, stream,
                     value, query, query_pos, Wc1t, Wvt, bc1, b_val, raw1, vout);

  // k3: head-XCD-affine sampling -> msd head-major (5000 blocks: 625 qg x 8 h)
  hipLaunchKernelGGL(k3_sample, dim3(5000), dim3(256), 0, stream,
                     raw1, refp, vout, msdb);

  // k4: out = msd @ W_out + b_out + query, head-major bf16 A direct, fp32 out + resid
  hipLaunchKernelGGL(k4g, dim3(1250), dim3(256), 0, stream,
                     msdb, Wot, b_out, query, out);
}